// Round 17
// baseline (343.121 us; speedup 1.0000x reference)
//
#include <hip/hip_runtime.h>

#define N_NODES 50000
#define N_EDGES 800000
#define GRID_G 782        // ceil(N_NODES/64) gemm blocks (64 rows/block; round-8 best)
#define NB_HIST 128       // histogram blocks
#define EPB (N_EDGES / NB_HIST)   // 6250 edges per hist block
#define WORDS 25000       // N_NODES/2 packed 2x16 words
#define NORMB_BLOCKS 98   // ceil(WORDS/256); each covers 512 nodes

typedef float f4 __attribute__((ext_vector_type(4)));  // native vec for nontemporal builtins

// ---------------- histogram degree count (no global atomics) ----------------
__global__ __launch_bounds__(256) void k_hist(const int* __restrict__ src,
                                              const int* __restrict__ dst,
                                              unsigned int* __restrict__ partO,
                                              unsigned int* __restrict__ partI) {
    __shared__ unsigned int h[12500];   // 50 KB: 25000 nodes packed 2 per word
    const int e0 = blockIdx.x * EPB;
    for (int kind = 0; kind < 2; ++kind) {
        const int* ids = kind ? dst : src;
        unsigned int* out = kind ? partI : partO;
        for (int p = 0; p < 2; ++p) {
            for (int i = threadIdx.x; i < 12500; i += 256) h[i] = 0;
            __syncthreads();
            const int base = p * 25000;
            for (int i = threadIdx.x; i < EPB; i += 256) {
                int id = ids[e0 + i] - base;
                if ((unsigned)id < 25000u)
                    atomicAdd(&h[id >> 1], (id & 1) ? 0x10000u : 1u);
            }
            __syncthreads();
            unsigned int* o = out + blockIdx.x * WORDS + p * 12500;
            for (int i = threadIdx.x; i < 12500; i += 256) o[i] = h[i];
            __syncthreads();
        }
    }
}

// ---------------- reduce partials -> degrees, norms, scan block-sums ----------------
__global__ __launch_bounds__(256) void k_normB(const unsigned int* __restrict__ partO,
                                               const unsigned int* __restrict__ partI,
                                               float* __restrict__ norm_src,
                                               float* __restrict__ norm_dst,
                                               int* __restrict__ deg_in,
                                               int* __restrict__ partials98) {
    __shared__ int sm4[4];
    int w = blockIdx.x * 256 + threadIdx.x;
    unsigned int lo_o = 0, hi_o = 0, lo_i = 0, hi_i = 0;
    if (w < WORDS) {
        for (int b = 0; b < NB_HIST; ++b) {
            unsigned int vo = partO[b * WORDS + w];
            unsigned int vi = partI[b * WORDS + w];
            lo_o += vo & 0xFFFFu; hi_o += vo >> 16;
            lo_i += vi & 0xFFFFu; hi_i += vi >> 16;
        }
        int n0 = 2 * w;
        *(float2*)&norm_src[n0] = make_float2(rsqrtf((float)max(lo_o, 1u)),
                                              rsqrtf((float)max(hi_o, 1u)));
        *(float2*)&norm_dst[n0] = make_float2(rsqrtf((float)max(lo_i, 1u)),
                                              rsqrtf((float)max(hi_i, 1u)));
        *(int2*)&deg_in[n0] = make_int2((int)lo_i, (int)hi_i);
    }
    int v = (int)(lo_i + hi_i);
#pragma unroll
    for (int off = 32; off > 0; off >>= 1) v += __shfl_down(v, off);
    int lane = threadIdx.x & 63, wv = threadIdx.x >> 6;
    if (lane == 0) sm4[wv] = v;
    __syncthreads();
    if (threadIdx.x == 0)
        partials98[blockIdx.x] = sm4[0] + sm4[1] + sm4[2] + sm4[3];
}

// ---------------- scan: exclusive prefix over deg_in (512 nodes/block) ----------------
__global__ __launch_bounds__(256) void k_scan(const int* __restrict__ deg_in,
                                              const int* __restrict__ partials98,
                                              int* __restrict__ row_start,
                                              int* __restrict__ cursor) {
    __shared__ int sm[256];
    __shared__ int carry_s;
    int t = threadIdx.x;
    if (t < 64) {
        int acc = 0;
        for (int i = t; i < blockIdx.x; i += 64) acc += partials98[i];
#pragma unroll
        for (int off = 32; off > 0; off >>= 1) acc += __shfl_down(acc, off);
        if (t == 0) carry_s = acc;
    }
    int n0 = blockIdx.x * 512 + t * 2;
    int a0 = 0, a1 = 0;
    if (n0 + 1 < N_NODES) {
        int2 d = *(const int2*)&deg_in[n0];
        a0 = d.x; a1 = d.y;
    } else if (n0 < N_NODES) {
        a0 = deg_in[n0];
    }
    sm[t] = a0 + a1;
    __syncthreads();
#pragma unroll
    for (int off = 1; off < 256; off <<= 1) {
        int tv = (t >= off) ? sm[t - off] : 0;
        __syncthreads();
        sm[t] += tv;
        __syncthreads();
    }
    int excl = sm[t] - (a0 + a1) + carry_s;
    if (n0 < N_NODES) { row_start[n0] = excl; cursor[n0] = excl; }
    if (n0 + 1 < N_NODES) { row_start[n0 + 1] = excl + a0; cursor[n0 + 1] = excl + a0; }
    if (blockIdx.x == 0 && t == 0) row_start[N_NODES] = N_EDGES;
}

// ---------------- async stage of one 32-k chunk (X: 64x32, W: 32x128) into LDS --------
// global_load_lds: LDS dest = wave-uniform base + lane*16B; global src per-lane.
// X chunk (8 KB) = 2 instrs/wave (8 rows each); W chunk (16 KB) = 4 instrs/wave.
// The compiler never auto-emits this (rounds 13/14: source-level reg pipelining got
// collapsed, VGPR stuck at 52, GEMM at 27% of HBM roofline). This binds the MLP.
__device__ __forceinline__ void stage_chunk(const float* __restrict__ X,
                                            const float* __restrict__ W,
                                            float* Xl, float* Wl,
                                            int bid, int kc, int tid) {
    const int wv = tid >> 6, l = tid & 63;
#pragma unroll
    for (int j = 0; j < 2; ++j) {
        int rl = wv * 16 + j * 8 + (l >> 3);
        int r = bid * 64 + rl; if (r > N_NODES - 1) r = N_NODES - 1;  // clamp OOB rows
        const float* g = X + (size_t)r * 128 + kc * 32 + (l & 7) * 4;
        float* d = Xl + (wv * 16 + j * 8) * 32;   // uniform base; lane*16B implicit
        __builtin_amdgcn_global_load_lds((__attribute__((address_space(1))) void*)g,
                                         (__attribute__((address_space(3))) void*)d,
                                         16, 0, 0);
    }
#pragma unroll
    for (int j = 0; j < 4; ++j) {
        const float* g = W + kc * 4096 + (wv * 4 + j) * 256 + l * 4;
        float* d = Wl + (wv * 4 + j) * 256;
        __builtin_amdgcn_global_load_lds((__attribute__((address_space(1))) void*)g,
                                         (__attribute__((address_space(3))) void*)d,
                                         16, 0, 0);
    }
}

// ---------------- GEMM body: G = X @ W (N,128)x(128,128), LDS double-buffered -------
// m97 pattern: issue next chunk's async loads, compute current chunk from LDS
// (1024 FMA ~ 2048 cy >> 900 cy HBM latency -> barrier drain ~free). Thread tile
// 4x8 (c0/c0+64, conflict-free W reads; X reads 4-way = ~1.6x on 1/3 of LDS ops,
// off critical path). LDS 48 KB -> 3 blocks/CU = grid residency (782/256).
__device__ __forceinline__ void gemm_body(const float* __restrict__ X,
                                          const float* __restrict__ W,
                                          float* __restrict__ G,
                                          float* Xl0, float* Xl1,
                                          float* Wl0, float* Wl1, int bid) {
    const int tid = threadIdx.x;
    const int tx = tid & 15;
    const int ty = tid >> 4;
    const int r0 = bid * 64 + ty * 4;
    const int c0 = tx * 4;

    float acc[2][4][4] = {};
    stage_chunk(X, W, Xl0, Wl0, bid, 0, tid);
    __syncthreads();   // drain prologue loads

#pragma unroll
    for (int kc = 0; kc < 4; ++kc) {
        float* Xcur = (kc & 1) ? Xl1 : Xl0;
        float* Wcur = (kc & 1) ? Wl1 : Wl0;
        if (kc < 3)
            stage_chunk(X, W, (kc & 1) ? Xl0 : Xl1, (kc & 1) ? Wl0 : Wl1, bid, kc + 1, tid);
#pragma unroll 2
        for (int ks = 0; ks < 32; ks += 4) {
            float4 xa[4];
#pragma unroll
            for (int i = 0; i < 4; ++i)
                xa[i] = *(const float4*)&Xcur[(ty * 4 + i) * 32 + ks];
#pragma unroll
            for (int kk = 0; kk < 4; ++kk) {
                float4 w0 = *(const float4*)&Wcur[(ks + kk) * 128 + c0];
                float4 w1 = *(const float4*)&Wcur[(ks + kk) * 128 + c0 + 64];
#pragma unroll
                for (int i = 0; i < 4; ++i) {
                    float a = (kk == 0) ? xa[i].x : (kk == 1) ? xa[i].y
                             : (kk == 2) ? xa[i].z : xa[i].w;
                    acc[0][i][0] = fmaf(a, w0.x, acc[0][i][0]);
                    acc[0][i][1] = fmaf(a, w0.y, acc[0][i][1]);
                    acc[0][i][2] = fmaf(a, w0.z, acc[0][i][2]);
                    acc[0][i][3] = fmaf(a, w0.w, acc[0][i][3]);
                    acc[1][i][0] = fmaf(a, w1.x, acc[1][i][0]);
                    acc[1][i][1] = fmaf(a, w1.y, acc[1][i][1]);
                    acc[1][i][2] = fmaf(a, w1.z, acc[1][i][2]);
                    acc[1][i][3] = fmaf(a, w1.w, acc[1][i][3]);
                }
            }
        }
        __syncthreads();   // drains next chunk's loads (completed under compute)
    }
#pragma unroll
    for (int i = 0; i < 4; ++i) {
        int r = r0 + i;
        if (r < N_NODES) {
            f4* p = (f4*)(G + (size_t)r * 128 + c0);
            f4 v0 = {acc[0][i][0], acc[0][i][1], acc[0][i][2], acc[0][i][3]};
            f4 v1 = {acc[1][i][0], acc[1][i][1], acc[1][i][2], acc[1][i][3]};
            __builtin_nontemporal_store(v0, p);
            __builtin_nontemporal_store(v1, p + 16);
        }
    }
}

__global__ __launch_bounds__(256, 4) void k_gemm(const float* __restrict__ X,
                                                 const float* __restrict__ W,
                                                 float* __restrict__ G) {
    __shared__ float Xl[2][2048];
    __shared__ float Wl[2][4096];
    gemm_body(X, W, G, &Xl[0][0], &Xl[1][0], &Wl[0][0], &Wl[1][0], blockIdx.x);
}

// ---------------- fused: GEMM1 (graph-independent) + CSR fill ----------------
__global__ __launch_bounds__(256, 4) void k_gemm_fill(const float* __restrict__ X,
                                                      const float* __restrict__ W,
                                                      float* __restrict__ G,
                                                      const int* __restrict__ src,
                                                      const int* __restrict__ dst,
                                                      const float* __restrict__ norm_src,
                                                      int* __restrict__ cursor,
                                                      int2* __restrict__ csr) {
    __shared__ float Xl[2][2048];
    __shared__ float Wl[2][4096];
    if (blockIdx.x < GRID_G) {
        gemm_body(X, W, G, &Xl[0][0], &Xl[1][0], &Wl[0][0], &Wl[1][0], blockIdx.x);
    } else {
        int e = (blockIdx.x - GRID_G) * 256 + threadIdx.x;
        if (e < N_EDGES) {
            int d = dst[e], s = src[e];
            int pos = atomicAdd(&cursor[d], 1);
            csr[pos] = make_int2(s, __float_as_int(norm_src[s]));
        }
    }
}

// ---------------- gather: Out[n] = act(norm_dst[n] * sum_e w_e * G[src_e] + b) ----------------
// Round-8 form (best measured): one wave per node, edge-pair scheme (lanes 0-31 even
// edges, 32-63 odd, float4 cols l*4..l*4+3, shfl_xor(32) combine), 8-wide loop.
template <int ELU, int PROJ>
__global__ __launch_bounds__(256) void k_gather(const float* __restrict__ G,
                                                const int* __restrict__ row_start,
                                                const int2* __restrict__ csr,
                                                const float* __restrict__ norm_dst,
                                                const float* __restrict__ bias,
                                                float* __restrict__ Out,
                                                const float* __restrict__ Wo,
                                                const float* __restrict__ bo,
                                                float* __restrict__ proj_out) {
    int n = (blockIdx.x * 256 + threadIdx.x) >> 6;
    int lane = threadIdx.x & 63;
    if (n >= N_NODES) return;
    const int half = lane >> 5;
    const int l = lane & 31;
    int e0 = row_start[n], e1 = row_start[n + 1];
    float4 a0 = {0,0,0,0}, a1 = {0,0,0,0}, a2 = {0,0,0,0}, a3 = {0,0,0,0};
    int e = e0;
    for (; e + 8 <= e1; e += 8) {
        int2 c0 = csr[e + half],     c1 = csr[e + 2 + half];
        int2 c2 = csr[e + 4 + half], c3 = csr[e + 6 + half];
        float4 g0 = *(const float4*)(G + (size_t)c0.x * 128 + l * 4);
        float4 g1 = *(const float4*)(G + (size_t)c1.x * 128 + l * 4);
        float4 g2 = *(const float4*)(G + (size_t)c2.x * 128 + l * 4);
        float4 g3 = *(const float4*)(G + (size_t)c3.x * 128 + l * 4);
        float w0 = __int_as_float(c0.y), w1 = __int_as_float(c1.y);
        float w2 = __int_as_float(c2.y), w3 = __int_as_float(c3.y);
        a0.x = fmaf(w0, g0.x, a0.x); a0.y = fmaf(w0, g0.y, a0.y);
        a0.z = fmaf(w0, g0.z, a0.z); a0.w = fmaf(w0, g0.w, a0.w);
        a1.x = fmaf(w1, g1.x, a1.x); a1.y = fmaf(w1, g1.y, a1.y);
        a1.z = fmaf(w1, g1.z, a1.z); a1.w = fmaf(w1, g1.w, a1.w);
        a2.x = fmaf(w2, g2.x, a2.x); a2.y = fmaf(w2, g2.y, a2.y);
        a2.z = fmaf(w2, g2.z, a2.z); a2.w = fmaf(w2, g2.w, a2.w);
        a3.x = fmaf(w3, g3.x, a3.x); a3.y = fmaf(w3, g3.y, a3.y);
        a3.z = fmaf(w3, g3.z, a3.z); a3.w = fmaf(w3, g3.w, a3.w);
    }
    for (; e < e1; e += 2) {
        int idx = e + half;
        if (idx < e1) {
            int2 c = csr[idx];
            float w = __int_as_float(c.y);
            float4 g = *(const float4*)(G + (size_t)c.x * 128 + l * 4);
            a0.x = fmaf(w, g.x, a0.x); a0.y = fmaf(w, g.y, a0.y);
            a0.z = fmaf(w, g.z, a0.z); a0.w = fmaf(w, g.w, a0.w);
        }
    }
    float4 s;
    s.x = (a0.x + a1.x) + (a2.x + a3.x);
    s.y = (a0.y + a1.y) + (a2.y + a3.y);
    s.z = (a0.z + a1.z) + (a2.z + a3.z);
    s.w = (a0.w + a1.w) + (a2.w + a3.w);
    s.x += __shfl_xor(s.x, 32);
    s.y += __shfl_xor(s.y, 32);
    s.z += __shfl_xor(s.z, 32);
    s.w += __shfl_xor(s.w, 32);
    float nd = norm_dst[n];
    float4 b = *(const float4*)(bias + l * 4);
    float4 o;
    o.x = fmaf(nd, s.x, b.x);
    o.y = fmaf(nd, s.y, b.y);
    o.z = fmaf(nd, s.z, b.z);
    o.w = fmaf(nd, s.w, b.w);
    if (ELU) {
        o.x = o.x > 0.f ? o.x : expm1f(o.x);
        o.y = o.y > 0.f ? o.y : expm1f(o.y);
        o.z = o.z > 0.f ? o.z : expm1f(o.z);
        o.w = o.w > 0.f ? o.w : expm1f(o.w);
    }
    if (half == 0)
        *(float4*)(Out + (size_t)n * 128 + l * 4) = o;
    if (PROJ) {
        float p0 = o.x * Wo[(l * 4 + 0) * 2] + o.y * Wo[(l * 4 + 1) * 2]
                 + o.z * Wo[(l * 4 + 2) * 2] + o.w * Wo[(l * 4 + 3) * 2];
        float p1 = o.x * Wo[(l * 4 + 0) * 2 + 1] + o.y * Wo[(l * 4 + 1) * 2 + 1]
                 + o.z * Wo[(l * 4 + 2) * 2 + 1] + o.w * Wo[(l * 4 + 3) * 2 + 1];
#pragma unroll
        for (int off = 16; off > 0; off >>= 1) {
            p0 += __shfl_down(p0, off);
            p1 += __shfl_down(p1, off);
        }
        if (lane == 0) {
            proj_out[n * 2 + 0] = p0 + bo[0];
            proj_out[n * 2 + 1] = p1 + bo[1];
        }
    }
}

extern "C" void kernel_launch(void* const* d_in, const int* in_sizes, int n_in,
                              void* d_out, int out_size, void* d_ws, size_t ws_size,
                              hipStream_t stream) {
    const float* x     = (const float*)d_in[0];
    const int*   src   = (const int*)d_in[1];
    const int*   dst   = (const int*)d_in[2];
    const float* W1    = (const float*)d_in[3];
    const float* b1    = (const float*)d_in[4];
    const float* W2    = (const float*)d_in[5];
    const float* b2    = (const float*)d_in[6];
    const float* W3    = (const float*)d_in[7];
    const float* b3    = (const float*)d_in[8];
    const float* W_out = (const float*)d_in[9];
    const float* b_out = (const float*)d_in[10];

    float* out = (float*)d_out;                 // n_out: N*2, then n_embed: N*128
    float* emb = out + (size_t)N_NODES * 2;

    char* ws = (char*)d_ws;
    float* norm_src  = (float*)(ws + 0);             // 200192
    float* norm_dst  = (float*)(ws + 200192);        // 200192
    int*   deg_in    = (int*)(ws + 400384);          // 200192
    int*   row_start = (int*)(ws + 600576);          // 200704 (N+1 ints)
    int*   cursor    = (int*)(ws + 801280);          // 200192
    int*   partials98= (int*)(ws + 1001472);         // 512
    int2*  csr       = (int2*)(ws + 1001984);        // 6,400,000
    float* bufA      = (float*)(ws + 7401984);       // 25,600,000
    float* bufB      = (float*)(ws + 33001984);      // 25,600,000  (end 58.6 MB)
    // partO/partI (12.8 MB each) alias bufA exactly; dead before gather1 writes bufA.
    unsigned int* partO = (unsigned int*)bufA;
    unsigned int* partI = partO + (size_t)NB_HIST * WORDS;

    const int gridW = (N_NODES * 64 + 255) / 256;      // 12500 (wave per node)
    const int gridF = GRID_G + (N_EDGES + 255) / 256;  // gemm + fill blocks

    k_hist<<<NB_HIST, 256, 0, stream>>>(src, dst, partO, partI);
    k_normB<<<NORMB_BLOCKS, 256, 0, stream>>>(partO, partI, norm_src, norm_dst,
                                              deg_in, partials98);
    k_scan<<<NORMB_BLOCKS, 256, 0, stream>>>(deg_in, partials98, row_start, cursor);
    // GEMM1 (x@W1, graph-independent) fused with CSR fill
    k_gemm_fill<<<gridF, 256, 0, stream>>>(x, W1, bufB, src, dst, norm_src,
                                           cursor, csr);
    k_gather<1, 0><<<gridW, 256, 0, stream>>>(bufB, row_start, csr, norm_dst, b1,
                                              bufA, nullptr, nullptr, nullptr);
    k_gemm<<<GRID_G, 256, 0, stream>>>(bufA, W2, bufB);
    k_gather<1, 0><<<gridW, 256, 0, stream>>>(bufB, row_start, csr, norm_dst, b2,
                                              bufA, nullptr, nullptr, nullptr);
    k_gemm<<<GRID_G, 256, 0, stream>>>(bufA, W3, bufB);
    k_gather<0, 1><<<gridW, 256, 0, stream>>>(bufB, row_start, csr, norm_dst, b3,
                                              emb, W_out, b_out, out);
}

// Round 18
// 323.439 us; speedup vs baseline: 1.0609x; 1.0609x over previous
//
#include <hip/hip_runtime.h>

#define N_NODES 50000
#define N_EDGES 800000
#define GRID_G 782        // ceil(N_NODES/64) gemm blocks (64 rows/block; round-8 best)
#define NB_HIST 128       // histogram blocks
#define EPB (N_EDGES / NB_HIST)   // 6250 edges per hist block
#define WORDS 25000       // N_NODES/2 packed 2x16 words
#define NORMB_BLOCKS 98   // ceil(WORDS/256); each covers 512 nodes

typedef float f4 __attribute__((ext_vector_type(4)));  // native vec for nontemporal builtins

// ---------------- histogram degree count (no global atomics) ----------------
__global__ __launch_bounds__(256) void k_hist(const int* __restrict__ src,
                                              const int* __restrict__ dst,
                                              unsigned int* __restrict__ partO,
                                              unsigned int* __restrict__ partI) {
    __shared__ unsigned int h[12500];   // 50 KB: 25000 nodes packed 2 per word
    const int e0 = blockIdx.x * EPB;
    for (int kind = 0; kind < 2; ++kind) {
        const int* ids = kind ? dst : src;
        unsigned int* out = kind ? partI : partO;
        for (int p = 0; p < 2; ++p) {
            for (int i = threadIdx.x; i < 12500; i += 256) h[i] = 0;
            __syncthreads();
            const int base = p * 25000;
            for (int i = threadIdx.x; i < EPB; i += 256) {
                int id = ids[e0 + i] - base;
                if ((unsigned)id < 25000u)
                    atomicAdd(&h[id >> 1], (id & 1) ? 0x10000u : 1u);
            }
            __syncthreads();
            unsigned int* o = out + blockIdx.x * WORDS + p * 12500;
            for (int i = threadIdx.x; i < 12500; i += 256) o[i] = h[i];
            __syncthreads();
        }
    }
}

// ---------------- reduce partials -> degrees, norms, scan block-sums ----------------
__global__ __launch_bounds__(256) void k_normB(const unsigned int* __restrict__ partO,
                                               const unsigned int* __restrict__ partI,
                                               float* __restrict__ norm_src,
                                               float* __restrict__ norm_dst,
                                               int* __restrict__ deg_in,
                                               int* __restrict__ partials98) {
    __shared__ int sm4[4];
    int w = blockIdx.x * 256 + threadIdx.x;
    unsigned int lo_o = 0, hi_o = 0, lo_i = 0, hi_i = 0;
    if (w < WORDS) {
        for (int b = 0; b < NB_HIST; ++b) {
            unsigned int vo = partO[b * WORDS + w];
            unsigned int vi = partI[b * WORDS + w];
            lo_o += vo & 0xFFFFu; hi_o += vo >> 16;
            lo_i += vi & 0xFFFFu; hi_i += vi >> 16;
        }
        int n0 = 2 * w;
        *(float2*)&norm_src[n0] = make_float2(rsqrtf((float)max(lo_o, 1u)),
                                              rsqrtf((float)max(hi_o, 1u)));
        *(float2*)&norm_dst[n0] = make_float2(rsqrtf((float)max(lo_i, 1u)),
                                              rsqrtf((float)max(hi_i, 1u)));
        *(int2*)&deg_in[n0] = make_int2((int)lo_i, (int)hi_i);
    }
    int v = (int)(lo_i + hi_i);
#pragma unroll
    for (int off = 32; off > 0; off >>= 1) v += __shfl_down(v, off);
    int lane = threadIdx.x & 63, wv = threadIdx.x >> 6;
    if (lane == 0) sm4[wv] = v;
    __syncthreads();
    if (threadIdx.x == 0)
        partials98[blockIdx.x] = sm4[0] + sm4[1] + sm4[2] + sm4[3];
}

// ---------------- scan: exclusive prefix over deg_in (512 nodes/block) ----------------
__global__ __launch_bounds__(256) void k_scan(const int* __restrict__ deg_in,
                                              const int* __restrict__ partials98,
                                              int* __restrict__ row_start,
                                              int* __restrict__ cursor) {
    __shared__ int sm[256];
    __shared__ int carry_s;
    int t = threadIdx.x;
    if (t < 64) {
        int acc = 0;
        for (int i = t; i < blockIdx.x; i += 64) acc += partials98[i];
#pragma unroll
        for (int off = 32; off > 0; off >>= 1) acc += __shfl_down(acc, off);
        if (t == 0) carry_s = acc;
    }
    int n0 = blockIdx.x * 512 + t * 2;
    int a0 = 0, a1 = 0;
    if (n0 + 1 < N_NODES) {
        int2 d = *(const int2*)&deg_in[n0];
        a0 = d.x; a1 = d.y;
    } else if (n0 < N_NODES) {
        a0 = deg_in[n0];
    }
    sm[t] = a0 + a1;
    __syncthreads();
#pragma unroll
    for (int off = 1; off < 256; off <<= 1) {
        int tv = (t >= off) ? sm[t - off] : 0;
        __syncthreads();
        sm[t] += tv;
        __syncthreads();
    }
    int excl = sm[t] - (a0 + a1) + carry_s;
    if (n0 < N_NODES) { row_start[n0] = excl; cursor[n0] = excl; }
    if (n0 + 1 < N_NODES) { row_start[n0 + 1] = excl + a0; cursor[n0 + 1] = excl + a0; }
    if (blockIdx.x == 0 && t == 0) row_start[N_NODES] = N_EDGES;
}

// ---------------- GEMM body: G = X @ W (N,128)x(128,128) ----------------
// Round-8 tile (best measured over 8 structural variants): 64 rows/block,
// thread 4x8 (c0/c0+64, conflict-free), W in two 32 KB chunks, direct HBM X loads.
// (Refuted: 2x8 tile r9, col-split r11, reg-prefetch r13/r14 (compiler collapses),
// global_load_lds dbuf r17 (bank conflicts + occupancy), (256,8) r7 (spill).)
__device__ __forceinline__ void gemm_body(const float* __restrict__ X,
                                          const float* __restrict__ W,
                                          float* __restrict__ G,
                                          float* __restrict__ Wl, int bid) {
    const int tx = threadIdx.x & 15;
    const int ty = threadIdx.x >> 4;
    const int r0 = bid * 64 + ty * 4;
    const int c0 = tx * 4;

    const float* xr[4];
#pragma unroll
    for (int i = 0; i < 4; ++i) {
        int r = r0 + i; if (r > N_NODES - 1) r = N_NODES - 1;
        xr[i] = X + (size_t)r * 128;
    }

    float acc[2][4][4] = {};
    for (int kc = 0; kc < 2; ++kc) {
        __syncthreads();
#pragma unroll
        for (int it = 0; it < 8; ++it) {
            int idx = threadIdx.x * 4 + it * 1024;
            *(float4*)&Wl[idx] = *(const float4*)&W[kc * 8192 + idx];
        }
        __syncthreads();
        const int kb = kc * 64;
#pragma unroll
        for (int kq = 0; kq < 4; ++kq) {          // 16-k batches
            float4 xa[4][4];
#pragma unroll
            for (int j = 0; j < 4; ++j)
#pragma unroll
                for (int i = 0; i < 4; ++i)
                    xa[i][j] = *(const float4*)(xr[i] + kb + kq * 16 + j * 4);
#pragma unroll
            for (int j = 0; j < 4; ++j) {
                const int ks = kq * 16 + j * 4;
#pragma unroll
                for (int kk = 0; kk < 4; ++kk) {
                    float4 w0 = *(const float4*)&Wl[(ks + kk) * 128 + c0];
                    float4 w1 = *(const float4*)&Wl[(ks + kk) * 128 + c0 + 64];
#pragma unroll
                    for (int i = 0; i < 4; ++i) {
                        float a = (kk == 0) ? xa[i][j].x : (kk == 1) ? xa[i][j].y
                                 : (kk == 2) ? xa[i][j].z : xa[i][j].w;
                        acc[0][i][0] = fmaf(a, w0.x, acc[0][i][0]);
                        acc[0][i][1] = fmaf(a, w0.y, acc[0][i][1]);
                        acc[0][i][2] = fmaf(a, w0.z, acc[0][i][2]);
                        acc[0][i][3] = fmaf(a, w0.w, acc[0][i][3]);
                        acc[1][i][0] = fmaf(a, w1.x, acc[1][i][0]);
                        acc[1][i][1] = fmaf(a, w1.y, acc[1][i][1]);
                        acc[1][i][2] = fmaf(a, w1.z, acc[1][i][2]);
                        acc[1][i][3] = fmaf(a, w1.w, acc[1][i][3]);
                    }
                }
            }
        }
    }
#pragma unroll
    for (int i = 0; i < 4; ++i) {
        int r = r0 + i;
        if (r < N_NODES) {
            f4* p = (f4*)(G + (size_t)r * 128 + c0);
            f4 v0 = {acc[0][i][0], acc[0][i][1], acc[0][i][2], acc[0][i][3]};
            f4 v1 = {acc[1][i][0], acc[1][i][1], acc[1][i][2], acc[1][i][3]};
            __builtin_nontemporal_store(v0, p);        // cols c0..c0+3
            __builtin_nontemporal_store(v1, p + 16);   // cols c0+64..
        }
    }
}

__global__ __launch_bounds__(256, 4) void k_gemm(const float* __restrict__ X,
                                                 const float* __restrict__ W,
                                                 float* __restrict__ G) {
    __shared__ float Wl[8192];
    gemm_body(X, W, G, Wl, blockIdx.x);
}

// ---------------- fused: GEMM1 (graph-independent) + CSR fill ----------------
__global__ __launch_bounds__(256, 4) void k_gemm_fill(const float* __restrict__ X,
                                                      const float* __restrict__ W,
                                                      float* __restrict__ G,
                                                      const int* __restrict__ src,
                                                      const int* __restrict__ dst,
                                                      const float* __restrict__ norm_src,
                                                      int* __restrict__ cursor,
                                                      int2* __restrict__ csr) {
    __shared__ float Wl[8192];
    if (blockIdx.x < GRID_G) {
        gemm_body(X, W, G, Wl, blockIdx.x);
    } else {
        int e = (blockIdx.x - GRID_G) * 256 + threadIdx.x;
        if (e < N_EDGES) {
            int d = dst[e], s = src[e];
            int pos = atomicAdd(&cursor[d], 1);
            csr[pos] = make_int2(s, __float_as_int(norm_src[s]));
        }
    }
}

// ---------------- gather: Out[n] = act(norm_dst[n] * sum_e w_e * G[src_e] + b) ----------------
// Round-8 form (best measured): one wave per node, edge-pair scheme (lanes 0-31 even
// edges, 32-63 odd, float4 cols l*4..l*4+3, shfl_xor(32) combine), 8-wide loop.
// (Refuted: 16-wide r10, csr sw-pipeline r8=neutral, LDS-tile fusion r12 = 2.3x worse.)
template <int ELU, int PROJ>
__global__ __launch_bounds__(256) void k_gather(const float* __restrict__ G,
                                                const int* __restrict__ row_start,
                                                const int2* __restrict__ csr,
                                                const float* __restrict__ norm_dst,
                                                const float* __restrict__ bias,
                                                float* __restrict__ Out,
                                                const float* __restrict__ Wo,
                                                const float* __restrict__ bo,
                                                float* __restrict__ proj_out) {
    int n = (blockIdx.x * 256 + threadIdx.x) >> 6;
    int lane = threadIdx.x & 63;
    if (n >= N_NODES) return;
    const int half = lane >> 5;
    const int l = lane & 31;
    int e0 = row_start[n], e1 = row_start[n + 1];
    float4 a0 = {0,0,0,0}, a1 = {0,0,0,0}, a2 = {0,0,0,0}, a3 = {0,0,0,0};
    int e = e0;
    for (; e + 8 <= e1; e += 8) {
        int2 c0 = csr[e + half],     c1 = csr[e + 2 + half];
        int2 c2 = csr[e + 4 + half], c3 = csr[e + 6 + half];
        float4 g0 = *(const float4*)(G + (size_t)c0.x * 128 + l * 4);
        float4 g1 = *(const float4*)(G + (size_t)c1.x * 128 + l * 4);
        float4 g2 = *(const float4*)(G + (size_t)c2.x * 128 + l * 4);
        float4 g3 = *(const float4*)(G + (size_t)c3.x * 128 + l * 4);
        float w0 = __int_as_float(c0.y), w1 = __int_as_float(c1.y);
        float w2 = __int_as_float(c2.y), w3 = __int_as_float(c3.y);
        a0.x = fmaf(w0, g0.x, a0.x); a0.y = fmaf(w0, g0.y, a0.y);
        a0.z = fmaf(w0, g0.z, a0.z); a0.w = fmaf(w0, g0.w, a0.w);
        a1.x = fmaf(w1, g1.x, a1.x); a1.y = fmaf(w1, g1.y, a1.y);
        a1.z = fmaf(w1, g1.z, a1.z); a1.w = fmaf(w1, g1.w, a1.w);
        a2.x = fmaf(w2, g2.x, a2.x); a2.y = fmaf(w2, g2.y, a2.y);
        a2.z = fmaf(w2, g2.z, a2.z); a2.w = fmaf(w2, g2.w, a2.w);
        a3.x = fmaf(w3, g3.x, a3.x); a3.y = fmaf(w3, g3.y, a3.y);
        a3.z = fmaf(w3, g3.z, a3.z); a3.w = fmaf(w3, g3.w, a3.w);
    }
    for (; e < e1; e += 2) {
        int idx = e + half;
        if (idx < e1) {
            int2 c = csr[idx];
            float w = __int_as_float(c.y);
            float4 g = *(const float4*)(G + (size_t)c.x * 128 + l * 4);
            a0.x = fmaf(w, g.x, a0.x); a0.y = fmaf(w, g.y, a0.y);
            a0.z = fmaf(w, g.z, a0.z); a0.w = fmaf(w, g.w, a0.w);
        }
    }
    float4 s;
    s.x = (a0.x + a1.x) + (a2.x + a3.x);
    s.y = (a0.y + a1.y) + (a2.y + a3.y);
    s.z = (a0.z + a1.z) + (a2.z + a3.z);
    s.w = (a0.w + a1.w) + (a2.w + a3.w);
    s.x += __shfl_xor(s.x, 32);
    s.y += __shfl_xor(s.y, 32);
    s.z += __shfl_xor(s.z, 32);
    s.w += __shfl_xor(s.w, 32);
    float nd = norm_dst[n];
    float4 b = *(const float4*)(bias + l * 4);
    float4 o;
    o.x = fmaf(nd, s.x, b.x);
    o.y = fmaf(nd, s.y, b.y);
    o.z = fmaf(nd, s.z, b.z);
    o.w = fmaf(nd, s.w, b.w);
    if (ELU) {
        o.x = o.x > 0.f ? o.x : expm1f(o.x);
        o.y = o.y > 0.f ? o.y : expm1f(o.y);
        o.z = o.z > 0.f ? o.z : expm1f(o.z);
        o.w = o.w > 0.f ? o.w : expm1f(o.w);
    }
    if (half == 0)
        *(float4*)(Out + (size_t)n * 128 + l * 4) = o;
    if (PROJ) {
        float p0 = o.x * Wo[(l * 4 + 0) * 2] + o.y * Wo[(l * 4 + 1) * 2]
                 + o.z * Wo[(l * 4 + 2) * 2] + o.w * Wo[(l * 4 + 3) * 2];
        float p1 = o.x * Wo[(l * 4 + 0) * 2 + 1] + o.y * Wo[(l * 4 + 1) * 2 + 1]
                 + o.z * Wo[(l * 4 + 2) * 2 + 1] + o.w * Wo[(l * 4 + 3) * 2 + 1];
#pragma unroll
        for (int off = 16; off > 0; off >>= 1) {
            p0 += __shfl_down(p0, off);
            p1 += __shfl_down(p1, off);
        }
        if (lane == 0) {
            proj_out[n * 2 + 0] = p0 + bo[0];
            proj_out[n * 2 + 1] = p1 + bo[1];
        }
    }
}

extern "C" void kernel_launch(void* const* d_in, const int* in_sizes, int n_in,
                              void* d_out, int out_size, void* d_ws, size_t ws_size,
                              hipStream_t stream) {
    const float* x     = (const float*)d_in[0];
    const int*   src   = (const int*)d_in[1];
    const int*   dst   = (const int*)d_in[2];
    const float* W1    = (const float*)d_in[3];
    const float* b1    = (const float*)d_in[4];
    const float* W2    = (const float*)d_in[5];
    const float* b2    = (const float*)d_in[6];
    const float* W3    = (const float*)d_in[7];
    const float* b3    = (const float*)d_in[8];
    const float* W_out = (const float*)d_in[9];
    const float* b_out = (const float*)d_in[10];

    float* out = (float*)d_out;                 // n_out: N*2, then n_embed: N*128
    float* emb = out + (size_t)N_NODES * 2;

    char* ws = (char*)d_ws;
    float* norm_src  = (float*)(ws + 0);             // 200192
    float* norm_dst  = (float*)(ws + 200192);        // 200192
    int*   deg_in    = (int*)(ws + 400384);          // 200192
    int*   row_start = (int*)(ws + 600576);          // 200704 (N+1 ints)
    int*   cursor    = (int*)(ws + 801280);          // 200192
    int*   partials98= (int*)(ws + 1001472);         // 512
    int2*  csr       = (int2*)(ws + 1001984);        // 6,400,000
    float* bufA      = (float*)(ws + 7401984);       // 25,600,000
    float* bufB      = (float*)(ws + 33001984);      // 25,600,000  (end 58.6 MB)
    // partO/partI (12.8 MB each) alias bufA exactly; dead before gather1 writes bufA.
    unsigned int* partO = (unsigned int*)bufA;
    unsigned int* partI = partO + (size_t)NB_HIST * WORDS;

    const int gridW = (N_NODES * 64 + 255) / 256;      // 12500 (wave per node)
    const int gridF = GRID_G + (N_EDGES + 255) / 256;  // gemm + fill blocks

    k_hist<<<NB_HIST, 256, 0, stream>>>(src, dst, partO, partI);
    k_normB<<<NORMB_BLOCKS, 256, 0, stream>>>(partO, partI, norm_src, norm_dst,
                                              deg_in, partials98);
    k_scan<<<NORMB_BLOCKS, 256, 0, stream>>>(deg_in, partials98, row_start, cursor);
    // GEMM1 (x@W1, graph-independent) fused with CSR fill
    k_gemm_fill<<<gridF, 256, 0, stream>>>(x, W1, bufB, src, dst, norm_src,
                                           cursor, csr);
    k_gather<1, 0><<<gridW, 256, 0, stream>>>(bufB, row_start, csr, norm_dst, b1,
                                              bufA, nullptr, nullptr, nullptr);
    k_gemm<<<GRID_G, 256, 0, stream>>>(bufA, W2, bufB);
    k_gather<1, 0><<<gridW, 256, 0, stream>>>(bufB, row_start, csr, norm_dst, b2,
                                              bufA, nullptr, nullptr, nullptr);
    k_gemm<<<GRID_G, 256, 0, stream>>>(bufA, W3, bufB);
    k_gather<0, 1><<<gridW, 256, 0, stream>>>(bufB, row_start, csr, norm_dst, b3,
                                              emb, W_out, b_out, out);
}